// Round 1
// 533.356 us; speedup vs baseline: 1.0662x; 1.0662x over previous
//
#include <hip/hip_runtime.h>
#include <cstddef>

#define T_STEPS  512
#define D_IN     5
#define NB       16      // batch elements per block
#define NTHREADS 1024    // 16 waves; each wave owns 1 L0 M-tile + 1 L1 M-tile
#define LOG2E    1.4426950408889634f

typedef __attribute__((ext_vector_type(8))) short f16x8;    // 8 fp16 (4 regs)
typedef __attribute__((ext_vector_type(4))) float f32x4;    // MFMA C/D

// A pinned in AGPRs ("a"); B, C, D in VGPRs (srcC and vDst must share a file).
// fp16 MFMA: 11-bit mantissa on BOTH operands beats the old bf16 hi/lo weight
// split (whose error was dominated by bf16 h at 2^-9 anyway) at HALF the MFMA
// count: 13 -> 7 per wave-step.
#define MFMA_INIT(D, A, B, C) \
    asm("v_mfma_f32_16x16x32_f16 %0, %1, %2, %3" : "=&v"(D) : "a"(A), "v"(B), "v"(C))
#define MFMA_ACC(D, A, B) \
    asm("v_mfma_f32_16x16x32_f16 %0, %1, %2, %0" : "+v"(D) : "a"(A), "v"(B))

__device__ __forceinline__ short f2h(float f) {             // RTNE fp32->fp16 bits
    return (short)__builtin_bit_cast(unsigned short, (_Float16)f);
}

// Weights pre-scaled by log2e (2*log2e for g-gate rows), so activations use
// v_exp_f32 (2^x) directly.  Fused products share one rcp:
//   sigma(i)*tanh(g) = (tg-1) / ((1+ui)(1+tg)),  tg=2^{2L g}, ui=2^{-L i}
// 8 trans ops per cell update instead of 10.
__device__ __forceinline__ float lstm_cell(const f32x4 acc, float& c) {
    const float tg = __builtin_amdgcn_exp2f(acc[2]);
    const float ui = __builtin_amdgcn_exp2f(-acc[0]);
    const float uf = __builtin_amdgcn_exp2f(-acc[1]);
    const float ig = (tg - 1.0f) * __builtin_amdgcn_rcpf((1.0f + ui) * (1.0f + tg));
    const float fz = __builtin_amdgcn_rcpf(1.0f + uf);
    c = fmaf(fz, c, ig);
    // clamp: 2^{2L c} overflows only if |c|>44; c is bounded ~O(3) in practice
    // but the clamp makes the fused form as overflow-safe as 1-2*rcp(1+t).
    const float ca = fminf(c * (2.0f * LOG2E), 126.0f);
    const float tc = __builtin_amdgcn_exp2f(ca);
    const float uo = __builtin_amdgcn_exp2f(-acc[3]);
    return (tc - 1.0f) * __builtin_amdgcn_rcpf((1.0f + uo) * (1.0f + tc));
}

// h-plane swizzle: row = 128 u16 = 16 x 16B blocks; block j of row n lives at
// j ^ (n & 7). b128 reads conflict-free; scalar b16 writes 2-way (free).
__device__ __forceinline__ int hswz(int n, int col) {
    return (((col >> 3) ^ (n & 7)) << 3) | (col & 7);
}

__global__ __launch_bounds__(NTHREADS, 4)
void lstm_stack_mfma7(const float* __restrict__ x,
                      const float* __restrict__ W_ih0,
                      const float* __restrict__ W_hh0,
                      const float* __restrict__ b_ih0,
                      const float* __restrict__ b_hh0,
                      const float* __restrict__ W_ih1,
                      const float* __restrict__ W_hh1,
                      const float* __restrict__ b_ih1,
                      const float* __restrict__ b_hh1,
                      const float* __restrict__ W1,
                      const float* __restrict__ b1,
                      const float* __restrict__ W2,
                      const float* __restrict__ b2,
                      float* __restrict__ out)
{
    __shared__ alignas(16) unsigned short h_hi[2][NB][128];  // fp16; k 0..63=h1, 64..127=h2 (swizzled)
    // x tile row = 40 u16 (20 dw): bank = 4*((5*n16+quad)%8), a permutation
    // mod 8 -> 2-way only.  Only slots 0..4 written (single fp16 x, no hi/lo);
    // slots 5..39 stay zero so quads 1-3 read zeros into the K=32 fragment.
    __shared__ alignas(16) unsigned short x_pack[2][NB][40];
    __shared__ alignas(16) float h2f[NB][68];   // exact fp32 h2(T-1) for FC head
    __shared__ alignas(16) float zb[NB][36];    // FC-head z buffer

    const int tid  = threadIdx.x;
    const int b0   = blockIdx.x * NB;
    const int w    = tid >> 6;        // wave 0..15 = M-tile index (both layers)
    const int lane = tid & 63;
    const int n16  = lane & 15;       // A row (within tile) / B col / C col
    const int quad = lane >> 4;       // A k-group / C row-group

    // ---------------- persistent register state ----------------
    f16x8 aX;                         // L0 x-weights (k<5 real, rest 0)
    f16x8 a0[2];                      // L0 h1 weights, K=64 (2 k-tiles)
    f16x8 a1[4];                      // L1 [h1;h2] weights, K=128 (4 k-tiles)
    f32x4 bc0, bc1;                   // bias C-operands (VGPR)
    float c0 = 0.f, c1 = 0.f;         // cell state (u = w*4+quad, b = n16)

    {
        const int u_a = w * 4 + (n16 >> 2);   // permuted u of this A row
        const int g_a = n16 & 3;              // gate of this A row (i,f,g,o)
        const int r0  = g_a * 64 + u_a;       // original weight row
        const float sc = (g_a == 2) ? 2.0f * LOG2E : LOG2E;   // exp2 pre-scale
        #pragma unroll
        for (int j = 0; j < 8; ++j) {
            const int k = quad * 8 + j;
            aX[j] = f2h(k < D_IN ? sc * W_ih0[r0 * D_IN + k] : 0.0f);
        }
        #pragma unroll
        for (int kt = 0; kt < 2; ++kt) {
            #pragma unroll
            for (int j = 0; j < 8; ++j)
                a0[kt][j] = f2h(sc * W_hh0[r0 * 64 + kt * 32 + quad * 8 + j]);
        }
        #pragma unroll
        for (int kt = 0; kt < 4; ++kt) {
            const int kg = kt * 32 + quad * 8;
            #pragma unroll
            for (int j = 0; j < 8; ++j)
                a1[kt][j] = f2h(sc * ((kg < 64) ? W_ih1[r0 * 64 + kg + j]
                                                : W_hh1[r0 * 64 + (kg - 64) + j]));
        }
        const int u_b = w * 4 + quad;
        #pragma unroll
        for (int r = 0; r < 4; ++r) {
            const float scr = (r == 2) ? 2.0f * LOG2E : LOG2E;
            bc0[r] = scr * (b_ih0[r * 64 + u_b] + b_hh0[r * 64 + u_b]);
            bc1[r] = scr * (b_ih1[r * 64 + u_b] + b_hh1[r * 64 + u_b]);
        }
    }

    // ---------------- LDS init ----------------
    for (int i = tid; i < 2 * NB * 128; i += NTHREADS) (&h_hi[0][0][0])[i] = 0;
    for (int i = tid; i < 2 * NB * 40; i += NTHREADS) (&x_pack[0][0][0])[i] = 0;
    __syncthreads();
    const int xb = tid / D_IN, xd = tid % D_IN;   // x-staging role (tid < 80)
    const bool xrole = (tid < NB * D_IN);
    if (xrole) {   // x(t=0) into buffer 0
        const float xv = x[((size_t)(b0 + xb) * T_STEPS) * D_IN + xd];
        x_pack[0][xb][xd] = (unsigned short)f2h(xv);
    }
    __syncthreads();

    const int u_c = w * 4 + quad;     // this lane's unit index, b = n16

    // step s: reads buf[s&1] = {h1(s-1), h2(s-2), x(s)}; L0 chain -> L1 chain
    // -> epi0 (VALU overlaps other waves' MFMAs) -> epi1.
    #pragma unroll 1
    for (int s = 0; s <= T_STEPS; ++s) {
        const int rb = s & 1, wbuf = rb ^ 1;

        float xv = 0.f;   // prefetch x(s+1)
        if (xrole && (s + 1) < T_STEPS)
            xv = x[((size_t)(b0 + xb) * T_STEPS + (s + 1)) * D_IN + xd];

        const f16x8 bxp = *reinterpret_cast<const f16x8*>(&x_pack[rb][n16][quad * 8]);
        f16x8 bhh[4];
        #pragma unroll
        for (int kt = 0; kt < 4; ++kt)
            bhh[kt] = *reinterpret_cast<const f16x8*>(
                &h_hi[rb][n16][((kt * 4 + quad) ^ (n16 & 7)) * 8]);

        f32x4 acc0, acc1;
        // ---- L0 chain (3 MFMAs) ----
        MFMA_INIT(acc0, aX, bxp, bc0);         // bias + x contribution
        MFMA_ACC(acc0, a0[0], bhh[0]);         // W . h1, k-tile 0
        MFMA_ACC(acc0, a0[1], bhh[1]);         // W . h1, k-tile 1
        // ---- L1 chain (4 MFMAs; provides acc0 hazard spacing) ----
        MFMA_INIT(acc1, a1[0], bhh[0], bc1);
        MFMA_ACC(acc1, a1[1], bhh[1]);
        MFMA_ACC(acc1, a1[2], bhh[2]);
        MFMA_ACC(acc1, a1[3], bhh[3]);

        // ---- L0 epilogue (acc0 hazard: 4 MFMA issues + nop > 16 cyc) ----
        asm("s_nop 7" : "+v"(acc0));
        if (s < T_STEPS) {
            const float h = lstm_cell(acc0, c0);
            h_hi[wbuf][n16][hswz(n16, u_c)] = (unsigned short)f2h(h);
        }

        // acc1 hazard: covered by the L0 epilogue in the steady state; the
        // extra nop covers the last iteration where the L0 epilogue is skipped.
        asm("s_nop 7" : "+v"(acc1));
        if (s > 0) {                // L1 epilogue: h2(s-1), c2
            const float h = lstm_cell(acc1, c1);
            h_hi[wbuf][n16][hswz(n16, 64 + u_c)] = (unsigned short)f2h(h);
            if (s == T_STEPS) h2f[n16][u_c] = h;   // exact h2(T-1) for FC head
        }
        if (xrole && (s + 1) < T_STEPS)     // stage x(s+1)
            x_pack[wbuf][xb][xd] = (unsigned short)f2h(xv);
        __syncthreads();
    }

    // ---------------- FC head: relu(h2_T @ W1^T + b1) @ W2^T + b2 ----------------
    if (tid < 512) {
        const int bb = tid >> 5;            // 0..15
        const int k  = tid & 31;            // 0..31
        float a = b1[k];
        #pragma unroll 16
        for (int j = 0; j < 64; ++j)
            a = fmaf(W1[k * 64 + j], h2f[bb][j], a);
        zb[bb][k] = fmaxf(a, 0.0f);
    }
    __syncthreads();
    if (tid < NB) {
        float a = b2[0];
        #pragma unroll
        for (int k = 0; k < 32; ++k) a = fmaf(W2[k], zb[tid][k], a);
        out[b0 + tid] = a;
    }
}

extern "C" void kernel_launch(void* const* d_in, const int* in_sizes, int n_in,
                              void* d_out, int out_size, void* d_ws, size_t ws_size,
                              hipStream_t stream) {
    (void)in_sizes; (void)n_in; (void)d_ws; (void)ws_size;
    const float* xp     = (const float*)d_in[0];
    const float* W_ih0  = (const float*)d_in[1];
    const float* W_hh0  = (const float*)d_in[2];
    const float* b_ih0  = (const float*)d_in[3];
    const float* b_hh0  = (const float*)d_in[4];
    const float* W_ih1  = (const float*)d_in[5];
    const float* W_hh1  = (const float*)d_in[6];
    const float* b_ih1  = (const float*)d_in[7];
    const float* b_hh1  = (const float*)d_in[8];
    const float* W1     = (const float*)d_in[9];
    const float* b1     = (const float*)d_in[10];
    const float* W2     = (const float*)d_in[11];
    const float* b2     = (const float*)d_in[12];
    float* outp = (float*)d_out;

    const int nblocks = out_size / NB;   // 4096/16 = 256, one block per CU
    hipLaunchKernelGGL(lstm_stack_mfma7, dim3(nblocks), dim3(NTHREADS), 0, stream,
                       xp, W_ih0, W_hh0, b_ih0, b_hh0,
                       W_ih1, W_hh1, b_ih1, b_hh1,
                       W1, b1, W2, b2, outp);
}

// Round 2
// 515.996 us; speedup vs baseline: 1.1021x; 1.0336x over previous
//
#include <hip/hip_runtime.h>
#include <cstddef>

#define T_STEPS  512
#define D_IN     5
#define NB       16      // batch elements per block
#define NTHREADS 1024    // 16 waves; each wave owns 1 L0 M-tile + 1 L1 M-tile
#define LOG2E    1.4426950408889634f

typedef __attribute__((ext_vector_type(8))) short f16x8;    // 8 fp16 (4 regs)
typedef __attribute__((ext_vector_type(4))) float f32x4;    // MFMA C/D

// A pinned in AGPRs ("a"); B, C, D in VGPRs.
#define MFMA_INIT(D, A, B, C) \
    asm("v_mfma_f32_16x16x32_f16 %0, %1, %2, %3" : "=&v"(D) : "a"(A), "v"(B), "v"(C))
#define MFMA_ACC(D, A, B) \
    asm("v_mfma_f32_16x16x32_f16 %0, %1, %2, %0" : "+v"(D) : "a"(A), "v"(B))

__device__ __forceinline__ short f2h(float f) {             // RTNE fp32->fp16 bits
    return (short)__builtin_bit_cast(unsigned short, (_Float16)f);
}

// Weights pre-scaled by log2e (2*log2e for g rows) so activations use v_exp_f32.
// Single-rcp cell update:  c' = c/(1+uf) + (tg-1)/((1+ui)(1+tg))
//                             = (c*B + (tg-1)*A) * rcp(A*B),  A=1+uf, B=(1+ui)(1+tg)
// 7 trans ops per cell (5 exp2 + 2 rcp), was 8.
__device__ __forceinline__ float lstm_cell(const f32x4 acc, float& c) {
    const float tg = __builtin_amdgcn_exp2f(acc[2]);
    const float ui = __builtin_amdgcn_exp2f(-acc[0]);
    const float uf = __builtin_amdgcn_exp2f(-acc[1]);
    const float A  = 1.0f + uf;
    const float Bd = (1.0f + ui) * (1.0f + tg);
    const float r  = __builtin_amdgcn_rcpf(A * Bd);
    c = fmaf(c, Bd, (tg - 1.0f) * A) * r;
    const float ca = fminf(c * (2.0f * LOG2E), 126.0f);
    const float tc = __builtin_amdgcn_exp2f(ca);
    const float uo = __builtin_amdgcn_exp2f(-acc[3]);
    return (tc - 1.0f) * __builtin_amdgcn_rcpf((1.0f + uo) * (1.0f + tc));
}

// h-plane swizzle: row = 64 u16 = 8 x 16B blocks; block j of row n lives at
// j ^ (n & 7). b128 reads conflict-free; scalar b16 writes 2-way (free).
__device__ __forceinline__ int hswz8(int n, int u) {
    return (((u >> 3) ^ (n & 7)) << 3) | (u & 7);
}

__global__ __launch_bounds__(NTHREADS, 4)
void lstm_stack_mfma8(const float* __restrict__ x,
                      const float* __restrict__ W_ih0,
                      const float* __restrict__ W_hh0,
                      const float* __restrict__ b_ih0,
                      const float* __restrict__ b_hh0,
                      const float* __restrict__ W_ih1,
                      const float* __restrict__ W_hh1,
                      const float* __restrict__ b_ih1,
                      const float* __restrict__ b_hh1,
                      const float* __restrict__ W1,
                      const float* __restrict__ b1,
                      const float* __restrict__ W2,
                      const float* __restrict__ b2,
                      float* __restrict__ out)
{
    // Lag-2 layer pipeline: interval t computes h1(t) (L0) and h2(t-2) (L1).
    // All planes double-buffered: write half p=t&1, read half q=p^1.
    __shared__ alignas(16) unsigned short h1b[2][NB][64];   // fp16 h1, swizzled
    __shared__ alignas(16) unsigned short h2b[2][NB][64];   // fp16 h2, swizzled
    // x row = 40 u16 (20 dw): bank = 4*((5*n16+quad)%8) -> 2-way only.
    // Slots 0..4 written; 5..39 stay zero (zeros feed quads 1-3 of the K=32 frag).
    __shared__ alignas(16) unsigned short x_pack[2][NB][40];
    __shared__ alignas(16) float h2f[NB][68];   // exact fp32 h2(T-1) for FC head
    __shared__ alignas(16) float zb[NB][36];    // FC-head z buffer

    const int tid  = threadIdx.x;
    const int b0   = blockIdx.x * NB;
    const int w    = tid >> 6;        // wave 0..15 = M-tile index (both layers)
    const int lane = tid & 63;
    const int n16  = lane & 15;       // A row (within tile) / B col / C col
    const int quad = lane >> 4;       // A k-group / C row-group

    // ---------------- persistent register state ----------------
    f16x8 aX;                         // L0 x-weights (k<5 real, rest 0)
    f16x8 a0[2];                      // L0 W_hh (on h1), K=64
    f16x8 a1h1[2];                    // L1 W_ih (on h1), K=64
    f16x8 a1h2[2];                    // L1 W_hh (on h2), K=64
    f32x4 bc0, bc1;                   // bias C-operands
    float c0 = 0.f, c1 = 0.f;         // cell states (u = w*4+quad, b = n16)

    {
        const int u_a = w * 4 + (n16 >> 2);   // permuted u of this A row
        const int g_a = n16 & 3;              // gate of this A row (i,f,g,o)
        const int r0  = g_a * 64 + u_a;       // original weight row
        const float sc = (g_a == 2) ? 2.0f * LOG2E : LOG2E;   // exp2 pre-scale
        #pragma unroll
        for (int j = 0; j < 8; ++j) {
            const int k = quad * 8 + j;
            aX[j] = f2h(k < D_IN ? sc * W_ih0[r0 * D_IN + k] : 0.0f);
        }
        #pragma unroll
        for (int kt = 0; kt < 2; ++kt) {
            #pragma unroll
            for (int j = 0; j < 8; ++j) {
                const int kk = kt * 32 + quad * 8 + j;
                a0[kt][j]   = f2h(sc * W_hh0[r0 * 64 + kk]);
                a1h1[kt][j] = f2h(sc * W_ih1[r0 * 64 + kk]);
                a1h2[kt][j] = f2h(sc * W_hh1[r0 * 64 + kk]);
            }
        }
        const int u_b = w * 4 + quad;
        #pragma unroll
        for (int r = 0; r < 4; ++r) {
            const float scr = (r == 2) ? 2.0f * LOG2E : LOG2E;
            bc0[r] = scr * (b_ih0[r * 64 + u_b] + b_hh0[r * 64 + u_b]);
            bc1[r] = scr * (b_ih1[r * 64 + u_b] + b_hh1[r * 64 + u_b]);
        }
    }

    // ---------------- LDS init ----------------
    for (int i = tid; i < 2 * NB * 64; i += NTHREADS) (&h1b[0][0][0])[i] = 0;
    for (int i = tid; i < 2 * NB * 64; i += NTHREADS) (&h2b[0][0][0])[i] = 0;
    for (int i = tid; i < 2 * NB * 40; i += NTHREADS) (&x_pack[0][0][0])[i] = 0;
    __syncthreads();
    const int xb = tid / D_IN, xd = tid % D_IN;   // x-staging role (tid < 80)
    const bool xrole = (tid < NB * D_IN);
    if (xrole) {   // x(0) -> buf 0, x(1) -> buf 1
        const size_t base = (size_t)(b0 + xb) * T_STEPS;
        x_pack[0][xb][xd] = (unsigned short)f2h(x[(base + 0) * D_IN + xd]);
        x_pack[1][xb][xd] = (unsigned short)f2h(x[(base + 1) * D_IN + xd]);
    }
    __syncthreads();

    const int u_c = w * 4 + quad;     // this lane's unit index, b = n16
    // loop-invariant LDS offsets (u16 units within a row)
    const int f0 = ((0 * 4 + quad) ^ (n16 & 7)) * 8;   // frag kt=0
    const int f1 = ((1 * 4 + quad) ^ (n16 & 7)) * 8;   // frag kt=1
    const int wo = hswz8(n16, u_c);                    // h write offset

    // cross-interval register pipeline:
    //   pacc0(t) = bc0 + Wx.x(t)           (computed at t-1; prologue for t=0)
    //   pacc1(t) = bc1 + W1h1.h1(t-2)      (computed at t-1; bc1 for t=0)
    f32x4 pacc0, pacc1;
    {
        const f16x8 bx0 = *reinterpret_cast<const f16x8*>(&x_pack[0][n16][quad * 8]);
        MFMA_INIT(pacc0, aX, bx0, bc0);
        pacc1 = bc1;
    }

    // interval t: serial chains are only 2 MFMAs deep per accumulator;
    // 3 slack MFMAs build pacc0/pacc1 for t+1 and fill the pipe while the
    // epilogues' trans chains run.
    #pragma unroll 1
    for (int t = 0; t <= T_STEPS + 1; ++t) {
        const int p = t & 1, q = p ^ 1;

        float xv = 0.f;   // prefetch x(t+2)
        if (xrole && (t + 2) < T_STEPS)
            xv = x[((size_t)(b0 + xb) * T_STEPS + (t + 2)) * D_IN + xd];

        const unsigned short* h1r = &h1b[q][n16][0];
        const unsigned short* h2r = &h2b[q][n16][0];
        const f16x8 bx = *reinterpret_cast<const f16x8*>(&x_pack[q][n16][quad * 8]); // x(t+1)
        f16x8 bh1[2], bh2[2];                       // h1(t-1), h2(t-3)
        bh1[0] = *reinterpret_cast<const f16x8*>(h1r + f0);
        bh1[1] = *reinterpret_cast<const f16x8*>(h1r + f1);
        bh2[0] = *reinterpret_cast<const f16x8*>(h2r + f0);
        bh2[1] = *reinterpret_cast<const f16x8*>(h2r + f1);

        f32x4 acc0, acc1;
        // ---- serial: L0 gates(t) and L1 gates(t-2) ----
        MFMA_INIT(acc0, a0[0],   bh1[0], pacc0);
        MFMA_ACC (acc0, a0[1],   bh1[1]);
        MFMA_INIT(acc1, a1h2[0], bh2[0], pacc1);
        MFMA_ACC (acc1, a1h2[1], bh2[1]);
        // ---- slack: build next interval's partial accumulators ----
        MFMA_INIT(pacc0, aX,      bx,     bc0);     // bc0 + Wx.x(t+1)
        MFMA_INIT(pacc1, a1h1[0], bh1[0], bc1);     // bc1 + W1h1.h1(t-1)
        MFMA_ACC (pacc1, a1h1[1], bh1[1]);

        // ---- L0 epilogue ----
        asm("s_nop 7\n\ts_nop 7" : "+v"(acc0));
        if (t < T_STEPS) {
            const float h = lstm_cell(acc0, c0);
            h1b[p][n16][wo] = (unsigned short)f2h(h);
        }
        // ---- L1 epilogue: h2(t-2) ----
        asm("s_nop 7\n\ts_nop 7" : "+v"(acc1));
        if (t >= 2) {
            const float h = lstm_cell(acc1, c1);
            h2b[p][n16][wo] = (unsigned short)f2h(h);
            if (t == T_STEPS + 1) h2f[n16][u_c] = h;   // exact h2(T-1) for FC head
        }
        if (xrole && (t + 2) < T_STEPS)     // stage x(t+2)
            x_pack[p][xb][xd] = (unsigned short)f2h(xv);
        __syncthreads();
    }

    // ---------------- FC head: relu(h2_T @ W1^T + b1) @ W2^T + b2 ----------------
    if (tid < 512) {
        const int bb = tid >> 5;            // 0..15
        const int k  = tid & 31;            // 0..31
        float a = b1[k];
        #pragma unroll 16
        for (int j = 0; j < 64; ++j)
            a = fmaf(W1[k * 64 + j], h2f[bb][j], a);
        zb[bb][k] = fmaxf(a, 0.0f);
    }
    __syncthreads();
    if (tid < NB) {
        float a = b2[0];
        #pragma unroll
        for (int k = 0; k < 32; ++k) a = fmaf(W2[k], zb[tid][k], a);
        out[b0 + tid] = a;
    }
}

extern "C" void kernel_launch(void* const* d_in, const int* in_sizes, int n_in,
                              void* d_out, int out_size, void* d_ws, size_t ws_size,
                              hipStream_t stream) {
    (void)in_sizes; (void)n_in; (void)d_ws; (void)ws_size;
    const float* xp     = (const float*)d_in[0];
    const float* W_ih0  = (const float*)d_in[1];
    const float* W_hh0  = (const float*)d_in[2];
    const float* b_ih0  = (const float*)d_in[3];
    const float* b_hh0  = (const float*)d_in[4];
    const float* W_ih1  = (const float*)d_in[5];
    const float* W_hh1  = (const float*)d_in[6];
    const float* b_ih1  = (const float*)d_in[7];
    const float* b_hh1  = (const float*)d_in[8];
    const float* W1     = (const float*)d_in[9];
    const float* b1     = (const float*)d_in[10];
    const float* W2     = (const float*)d_in[11];
    const float* b2     = (const float*)d_in[12];
    float* outp = (float*)d_out;

    const int nblocks = out_size / NB;   // 4096/16 = 256, one block per CU
    hipLaunchKernelGGL(lstm_stack_mfma8, dim3(nblocks), dim3(NTHREADS), 0, stream,
                       xp, W_ih0, W_hh0, b_ih0, b_hh0,
                       W_ih1, W_hh1, b_ih1, b_hh1,
                       W1, b1, W2, b2, outp);
}